// Round 9
// baseline (211.301 us; speedup 1.0000x reference)
//
#include <hip/hip_runtime.h>
#include <hip/hip_bf16.h>

#define BSZ   2
#define LSEQ  4096
#define DH    512
#define NH    8
#define HDIM  64

typedef unsigned short ushort_t;
typedef __attribute__((ext_vector_type(8))) short s8v;    // 8 bf16 = 4 VGPRs
typedef __attribute__((ext_vector_type(4))) float f4v;    // MFMA accumulator

__device__ __forceinline__ ushort_t f2bf(float f) {
    __hip_bfloat16 h = __float2bfloat16(f);
    return *(ushort_t*)&h;
}

// async global->LDS, 16B per lane; LDS dest = wave-uniform base + lane*16B
__device__ __forceinline__ void gld_lds16(const ushort_t* g, ushort_t* l) {
    __builtin_amdgcn_global_load_lds(
        (const __attribute__((address_space(1))) void*)g,
        (__attribute__((address_space(3))) void*)l, 16, 0, 0);
}

// ---------------------------------------------------------------------------
// Fused prep: [0,4096) cast x->bf16 ; [4096,4864) transpose w_in ;
// [4864,5120) transpose w_out. One launch instead of three.
// ---------------------------------------------------------------------------
__device__ __forceinline__ void transpose_tile(const float* __restrict__ src,
                                               ushort_t* __restrict__ dst,
                                               int R, int C, int bx, int by)
{
    __shared__ float tile[32][33];
    int r0 = by * 32, c0 = bx * 32;
    int t = threadIdx.x;
    int tr = t >> 5, tc = t & 31;
    #pragma unroll
    for (int i = 0; i < 4; i++)
        tile[tr + 8 * i][tc] = src[(size_t)(r0 + tr + 8 * i) * C + c0 + tc];
    __syncthreads();
    #pragma unroll
    for (int i = 0; i < 4; i++) {
        int oc = tr + 8 * i;
        dst[(size_t)(c0 + oc) * R + r0 + tc] = f2bf(tile[tc][oc]);
    }
}

__global__ __launch_bounds__(256) void prep(const float* __restrict__ x,
                                            ushort_t* __restrict__ xb,
                                            const float* __restrict__ w_in,
                                            ushort_t* __restrict__ w_inT,
                                            const float* __restrict__ w_out,
                                            ushort_t* __restrict__ w_outT)
{
    int bx = blockIdx.x;
    if (bx < 4096) {
        int i = (bx * 256 + threadIdx.x) * 4;
        float4 v = *(const float4*)&x[i];
        ushort_t o[4] = {f2bf(v.x), f2bf(v.y), f2bf(v.z), f2bf(v.w)};
        *(uint2*)&xb[i] = *(uint2*)o;
    } else if (bx < 4864) {
        int idx = bx - 4096;                     // w_in: [512][1536] -> [1536][512]
        transpose_tile(w_in, w_inT, DH, 3 * DH, idx % 48, idx / 48);
    } else {
        int idx = bx - 4864;                     // w_out: [512][512]
        transpose_tile(w_out, w_outT, DH, DH, idx % 16, idx / 16);
    }
}

// ---------------------------------------------------------------------------
__global__ __launch_bounds__(256) void vtrans(const ushort_t* __restrict__ qkv,
                                              ushort_t* __restrict__ vt)
{
    __shared__ ushort_t T[64][72];
    const int lt = blockIdx.x, h = blockIdx.y, b = blockIdx.z;
    const int l0 = lt * 64;
    const int t = threadIdx.x;
    {
        int r = t >> 2, c = (t & 3) * 16;
        size_t g = ((size_t)(b * LSEQ + l0 + r)) * (3 * DH) + 2 * DH + h * HDIM + c;
        *(uint4*)&T[r][c]     = *(const uint4*)&qkv[g];
        *(uint4*)&T[r][c + 8] = *(const uint4*)&qkv[g + 8];
    }
    __syncthreads();
    {
        int d = t >> 2, cl = (t & 3) * 16;
        ushort_t tmp[16];
        #pragma unroll
        for (int j = 0; j < 16; j++) tmp[j] = T[cl + j][d];
        size_t g = ((size_t)((b * NH + h) * 64 + d)) * LSEQ + l0 + cl;
        *(uint4*)&vt[g]     = *(uint4*)&tmp[0];
        *(uint4*)&vt[g + 8] = *(uint4*)&tmp[8];
    }
}

// ---------------------------------------------------------------------------
// bf16 MFMA GEMM (m97 structure), unchanged.
// ---------------------------------------------------------------------------
template <typename OUT>
__global__ __launch_bounds__(256) void gemm_bt(const ushort_t* __restrict__ A,
                                               const ushort_t* __restrict__ Bt,
                                               const float* __restrict__ bias,
                                               OUT* __restrict__ C,
                                               int M, int N, int K)
{
    __shared__ ushort_t As[128 * 32];
    __shared__ ushort_t Bs[128 * 32];
    const int tid = threadIdx.x;
    const int row0 = blockIdx.y * 128, col0 = blockIdx.x * 128;
    const int wid = tid >> 6, lane = tid & 63;
    const int wm = wid >> 1, wn = wid & 1;
    const int quad = lane >> 4, ln = lane & 15;

    f4v acc[4][4] = {};

    const int srow = (lane >> 2);
    const int scol = (lane & 3) * 8;

    for (int k0 = 0; k0 < K; k0 += 32) {
        #pragma unroll
        for (int t = 0; t < 2; t++) {
            int chunk = wid * 2 + t;
            int r = chunk * 16 + srow;
            gld_lds16(&A[(size_t)(row0 + r) * K + k0 + scol], &As[chunk * 512]);
            gld_lds16(&Bt[(size_t)(col0 + r) * K + k0 + scol], &Bs[chunk * 512]);
        }
        __syncthreads();
        s8v af[4], bf[4];
        #pragma unroll
        for (int mt = 0; mt < 4; mt++)
            af[mt] = *(const s8v*)&As[(wm * 64 + mt * 16 + ln) * 32 + quad * 8];
        #pragma unroll
        for (int nt = 0; nt < 4; nt++)
            bf[nt] = *(const s8v*)&Bs[(wn * 64 + nt * 16 + ln) * 32 + quad * 8];
        #pragma unroll
        for (int mt = 0; mt < 4; mt++)
            #pragma unroll
            for (int nt = 0; nt < 4; nt++)
                acc[mt][nt] = __builtin_amdgcn_mfma_f32_16x16x32_bf16(
                    af[mt], bf[nt], acc[mt][nt], 0, 0, 0);
        __syncthreads();
    }

    #pragma unroll
    for (int mt = 0; mt < 4; mt++) {
        #pragma unroll
        for (int nt = 0; nt < 4; nt++) {
            int c = col0 + wn * 64 + nt * 16 + ln;
            float bv = bias[c];
            #pragma unroll
            for (int reg = 0; reg < 4; reg++) {
                int r = row0 + wm * 64 + mt * 16 + quad * 4 + reg;
                float v = acc[mt][nt][reg] + bv;
                if constexpr (sizeof(OUT) == 2)
                    C[(size_t)r * N + c] = (OUT)f2bf(v);
                else
                    C[(size_t)r * N + c] = v;
            }
        }
    }
}

// ---------------------------------------------------------------------------
// Flash v6: 2 waves x 32 q-rows = full 64-row tile per block; K/V fragment
// reads amortized over 2x MFMA per wave; staging once per tile. Uniform pair
// schedule {63-p, p} -> 512 blocks x 65 iters, no triangular tail.
// ---------------------------------------------------------------------------
__global__ __launch_bounds__(128) void flash_mfma(const ushort_t* __restrict__ qkv,
                                                  const ushort_t* __restrict__ vt,
                                                  ushort_t* __restrict__ att)
{
    __shared__ ushort_t Ks[64 * 72];   // [kseq][d]
    __shared__ ushort_t Vs[64 * 72];   // [d][kseq]
    __shared__ ushort_t Ps[64 * 72];   // [q][kseq]

    const int p = blockIdx.x;          // 0..31
    const int h = blockIdx.y, b = blockIdx.z;
    const int tid = threadIdx.x;
    const int w = tid >> 6, lane = tid & 63;   // w in {0,1}
    const int quad = lane >> 4, ln = lane & 15;

    const int sr = tid >> 1, sc = (tid & 1) * 32;   // staging: 2 threads/row
    const int ldsw = sr * 72 + sc;
    const size_t kstep = (size_t)64 * 3 * DH;
    const float C_EXP = 0.18033688011112042f;  // 0.125 * log2(e)

    const int qts[2] = {63 - p, p};

    for (int ti = 0; ti < 2; ti++) {
        const int qt = qts[ti], q0 = qt * 64;
        const int qrow0 = q0 + w * 32;           // this wave's 32 q-rows

        // Q B-frags for both q-groups, loop-invariant, direct from global
        s8v qa[2][2];
        #pragma unroll
        for (int qg = 0; qg < 2; qg++) {
            const ushort_t* qrow = qkv
                + ((size_t)(b * LSEQ + qrow0 + qg * 16 + ln)) * (3 * DH) + h * HDIM;
            qa[qg][0] = *(const s8v*)(qrow + quad * 8);
            qa[qg][1] = *(const s8v*)(qrow + 32 + quad * 8);
        }

        float l_s[2] = {0.0f, 0.0f};
        f4v o_acc[2][4] = {};

        size_t gk = ((size_t)(b * LSEQ + sr)) * (3 * DH) + DH + h * HDIM + sc;
        size_t gv = ((size_t)((b * NH + h) * 64 + sr)) * LSEQ + sc;
        uint4 pk0 = *(const uint4*)&qkv[gk];
        uint4 pk1 = *(const uint4*)&qkv[gk + 8];
        uint4 pk2 = *(const uint4*)&qkv[gk + 16];
        uint4 pk3 = *(const uint4*)&qkv[gk + 24];
        uint4 pv0 = *(const uint4*)&vt[gv];
        uint4 pv1 = *(const uint4*)&vt[gv + 8];
        uint4 pv2 = *(const uint4*)&vt[gv + 16];
        uint4 pv3 = *(const uint4*)&vt[gv + 24];

        for (int kt = 0; kt <= qt; kt++) {
            const int k0 = kt * 64;
            __syncthreads();   // all waves done reading prev Ks/Vs
            *(uint4*)&Ks[ldsw]      = pk0;
            *(uint4*)&Ks[ldsw + 8]  = pk1;
            *(uint4*)&Ks[ldsw + 16] = pk2;
            *(uint4*)&Ks[ldsw + 24] = pk3;
            *(uint4*)&Vs[ldsw]      = pv0;
            *(uint4*)&Vs[ldsw + 8]  = pv1;
            *(uint4*)&Vs[ldsw + 16] = pv2;
            *(uint4*)&Vs[ldsw + 24] = pv3;
            if (kt < qt) {
                gk += kstep; gv += 64;
                pk0 = *(const uint4*)&qkv[gk];
                pk1 = *(const uint4*)&qkv[gk + 8];
                pk2 = *(const uint4*)&qkv[gk + 16];
                pk3 = *(const uint4*)&qkv[gk + 24];
                pv0 = *(const uint4*)&vt[gv];
                pv1 = *(const uint4*)&vt[gv + 8];
                pv2 = *(const uint4*)&vt[gv + 16];
                pv3 = *(const uint4*)&vt[gv + 24];
            }
            __syncthreads();

            // shared fragments: full K tile + full V tile, read ONCE per wave
            s8v kb[4][2], vb[4][2];
            #pragma unroll
            for (int nt = 0; nt < 4; nt++) {
                kb[nt][0] = *(const s8v*)&Ks[(nt * 16 + ln) * 72 + quad * 8];
                kb[nt][1] = *(const s8v*)&Ks[(nt * 16 + ln) * 72 + 32 + quad * 8];
            }
            #pragma unroll
            for (int dt = 0; dt < 4; dt++) {
                vb[dt][0] = *(const s8v*)&Vs[(dt * 16 + ln) * 72 + quad * 8];
                vb[dt][1] = *(const s8v*)&Vs[(dt * 16 + ln) * 72 + 32 + quad * 8];
            }

            #pragma unroll
            for (int qg = 0; qg < 2; qg++) {
                // S^T[k0+nt*16+quad*4+reg][qrow0+qg*16+ln]
                f4v s[4] = {};
                #pragma unroll
                for (int nt = 0; nt < 4; nt++) {
                    s[nt] = __builtin_amdgcn_mfma_f32_16x16x32_bf16(kb[nt][0], qa[qg][0], s[nt], 0, 0, 0);
                    s[nt] = __builtin_amdgcn_mfma_f32_16x16x32_bf16(kb[nt][1], qa[qg][1], s[nt], 0, 0, 0);
                }

                float pp[4][4];
                const int q = qrow0 + qg * 16 + ln;
                if (kt == qt) {
                    #pragma unroll
                    for (int nt = 0; nt < 4; nt++) {
                        #pragma unroll
                        for (int reg = 0; reg < 4; reg++) {
                            int kidx = k0 + nt * 16 + quad * 4 + reg;
                            bool valid = (kidx <= q) && (kidx >= 1 || q == 0);
                            pp[nt][reg] = valid ? __builtin_amdgcn_exp2f(s[nt][reg] * C_EXP) : 0.0f;
                        }
                    }
                } else {
                    #pragma unroll
                    for (int nt = 0; nt < 4; nt++)
                        #pragma unroll
                        for (int reg = 0; reg < 4; reg++)
                            pp[nt][reg] = __builtin_amdgcn_exp2f(s[nt][reg] * C_EXP);
                    if (kt == 0 && quad == 0)   // k==0 invalid (q >= 64 here)
                        pp[0][0] = 0.0f;
                }

                #pragma unroll
                for (int nt = 0; nt < 4; nt++)
                    l_s[qg] += (pp[nt][0] + pp[nt][1]) + (pp[nt][2] + pp[nt][3]);

                const int prow = (w * 32 + qg * 16 + ln) * 72;
                #pragma unroll
                for (int nt = 0; nt < 4; nt++) {
                    unsigned int lo = (unsigned int)f2bf(pp[nt][0]) | ((unsigned int)f2bf(pp[nt][1]) << 16);
                    unsigned int hi = (unsigned int)f2bf(pp[nt][2]) | ((unsigned int)f2bf(pp[nt][3]) << 16);
                    uint2 pkd; pkd.x = lo; pkd.y = hi;
                    *(uint2*)&Ps[prow + nt * 16 + quad * 4] = pkd;
                }
                // wave-private rows: no barrier

                s8v pa0 = *(const s8v*)&Ps[prow + quad * 8];
                s8v pa1 = *(const s8v*)&Ps[prow + 32 + quad * 8];
                #pragma unroll
                for (int dt = 0; dt < 4; dt++) {
                    o_acc[qg][dt] = __builtin_amdgcn_mfma_f32_16x16x32_bf16(pa0, vb[dt][0], o_acc[qg][dt], 0, 0, 0);
                    o_acc[qg][dt] = __builtin_amdgcn_mfma_f32_16x16x32_bf16(pa1, vb[dt][1], o_acc[qg][dt], 0, 0, 0);
                }
            }
        }

        // epilogue per q-group: reduce l over quads, normalize, write
        #pragma unroll
        for (int qg = 0; qg < 2; qg++) {
            float lf = l_s[qg];
            lf += __shfl_xor(lf, 16);
            lf += __shfl_xor(lf, 32);
            #pragma unroll
            for (int reg = 0; reg < 4; reg++) {
                float linv = 1.0f / __shfl(lf, quad * 4 + reg);
                size_t r = (size_t)(b * LSEQ + qrow0 + qg * 16 + quad * 4 + reg);
                #pragma unroll
                for (int dt = 0; dt < 4; dt++)
                    att[r * DH + h * HDIM + dt * 16 + ln] = f2bf(o_acc[qg][dt][reg] * linv);
            }
        }
    }
}

// ---------------------------------------------------------------------------
extern "C" void kernel_launch(void* const* d_in, const int* in_sizes, int n_in,
                              void* d_out, int out_size, void* d_ws, size_t ws_size,
                              hipStream_t stream)
{
    const float* x     = (const float*)d_in[0];  // [2,4096,512]
    const float* w_in  = (const float*)d_in[1];  // [512,1536]
    const float* b_in  = (const float*)d_in[2];  // [1536]
    const float* w_out = (const float*)d_in[3];  // [512,512]
    const float* b_out = (const float*)d_in[4];  // [512]
    float* out = (float*)d_out;                  // [2,4096,512] fp32

    const int M = BSZ * LSEQ;                    // 8192
    char* ws = (char*)d_ws;
    ushort_t* xb    = (ushort_t*)ws;                       ws += (size_t)M * DH * 2;
    ushort_t* w_inT = (ushort_t*)ws;                       ws += (size_t)3 * DH * DH * 2;
    ushort_t* w_outT= (ushort_t*)ws;                       ws += (size_t)DH * DH * 2;
    ushort_t* qkvb  = (ushort_t*)ws;                       ws += (size_t)M * 3 * DH * 2;
    ushort_t* vtb   = (ushort_t*)ws;                       ws += (size_t)M * DH * 2;
    ushort_t* attb  = (ushort_t*)ws;

    prep<<<5120, 256, 0, stream>>>(x, xb, w_in, w_inT, w_out, w_outT);

    gemm_bt<ushort_t><<<dim3(3 * DH / 128, M / 128), 256, 0, stream>>>(
        xb, w_inT, b_in, qkvb, M, 3 * DH, DH);

    vtrans<<<dim3(LSEQ / 64, NH, BSZ), 256, 0, stream>>>(qkvb, vtb);

    flash_mfma<<<dim3(32, NH, BSZ), 128, 0, stream>>>(qkvb, vtb, attb);

    gemm_bt<float><<<dim3(DH / 128, M / 128), 256, 0, stream>>>(
        attb, w_outT, b_out, out, M, DH, DH);
}

// Round 10
// 194.617 us; speedup vs baseline: 1.0857x; 1.0857x over previous
//
#include <hip/hip_runtime.h>
#include <hip/hip_bf16.h>

#define BSZ   2
#define LSEQ  4096
#define DH    512
#define NH    8
#define HDIM  64

typedef unsigned short ushort_t;
typedef __attribute__((ext_vector_type(8))) short s8v;    // 8 bf16 = 4 VGPRs
typedef __attribute__((ext_vector_type(4))) float f4v;    // MFMA accumulator

__device__ __forceinline__ ushort_t f2bf(float f) {
    __hip_bfloat16 h = __float2bfloat16(f);
    return *(ushort_t*)&h;
}

// async global->LDS, 16B per lane; LDS dest = wave-uniform base + lane*16B
__device__ __forceinline__ void gld_lds16(const ushort_t* g, ushort_t* l) {
    __builtin_amdgcn_global_load_lds(
        (const __attribute__((address_space(1))) void*)g,
        (__attribute__((address_space(3))) void*)l, 16, 0, 0);
}

// ---------------------------------------------------------------------------
// Fused prep: cast x->bf16, transpose both weights, zero O/l accumulators.
// blocks: [0,4096) x-cast | [4096,4864) w_in^T | [4864,5120) w_out^T |
//         [5120,9216) zero Oacc | [9216,9280) zero lacc
// ---------------------------------------------------------------------------
__device__ __forceinline__ void transpose_tile(const float* __restrict__ src,
                                               ushort_t* __restrict__ dst,
                                               int R, int C, int bx, int by)
{
    __shared__ float tile[32][33];
    int r0 = by * 32, c0 = bx * 32;
    int t = threadIdx.x;
    int tr = t >> 5, tc = t & 31;
    #pragma unroll
    for (int i = 0; i < 4; i++)
        tile[tr + 8 * i][tc] = src[(size_t)(r0 + tr + 8 * i) * C + c0 + tc];
    __syncthreads();
    #pragma unroll
    for (int i = 0; i < 4; i++) {
        int oc = tr + 8 * i;
        dst[(size_t)(c0 + oc) * R + r0 + tc] = f2bf(tile[tc][oc]);
    }
}

__global__ __launch_bounds__(256) void prep(const float* __restrict__ x,
                                            ushort_t* __restrict__ xb,
                                            const float* __restrict__ w_in,
                                            ushort_t* __restrict__ w_inT,
                                            const float* __restrict__ w_out,
                                            ushort_t* __restrict__ w_outT,
                                            float* __restrict__ Oacc,
                                            float* __restrict__ lacc)
{
    int bx = blockIdx.x;
    if (bx < 4096) {
        int i = (bx * 256 + threadIdx.x) * 4;
        float4 v = *(const float4*)&x[i];
        ushort_t o[4] = {f2bf(v.x), f2bf(v.y), f2bf(v.z), f2bf(v.w)};
        *(uint2*)&xb[i] = *(uint2*)o;
    } else if (bx < 4864) {
        int idx = bx - 4096;                     // w_in: [512][1536] -> [1536][512]
        transpose_tile(w_in, w_inT, DH, 3 * DH, idx % 48, idx / 48);
    } else if (bx < 5120) {
        int idx = bx - 4864;                     // w_out: [512][512]
        transpose_tile(w_out, w_outT, DH, DH, idx % 16, idx / 16);
    } else if (bx < 9216) {
        int i = ((bx - 5120) * 256 + threadIdx.x) * 4;   // zero Oacc (4.2M floats)
        float4 z = {0.f, 0.f, 0.f, 0.f};
        *(float4*)&Oacc[i] = z;
    } else {
        int i = ((bx - 9216) * 256 + threadIdx.x) * 4;   // zero lacc (64K floats)
        float4 z = {0.f, 0.f, 0.f, 0.f};
        *(float4*)&lacc[i] = z;
    }
}

// ---------------------------------------------------------------------------
__global__ __launch_bounds__(256) void vtrans(const ushort_t* __restrict__ qkv,
                                              ushort_t* __restrict__ vt)
{
    __shared__ ushort_t T[64][72];
    const int lt = blockIdx.x, h = blockIdx.y, b = blockIdx.z;
    const int l0 = lt * 64;
    const int t = threadIdx.x;
    {
        int r = t >> 2, c = (t & 3) * 16;
        size_t g = ((size_t)(b * LSEQ + l0 + r)) * (3 * DH) + 2 * DH + h * HDIM + c;
        *(uint4*)&T[r][c]     = *(const uint4*)&qkv[g];
        *(uint4*)&T[r][c + 8] = *(const uint4*)&qkv[g + 8];
    }
    __syncthreads();
    {
        int d = t >> 2, cl = (t & 3) * 16;
        ushort_t tmp[16];
        #pragma unroll
        for (int j = 0; j < 16; j++) tmp[j] = T[cl + j][d];
        size_t g = ((size_t)((b * NH + h) * 64 + d)) * LSEQ + l0 + cl;
        *(uint4*)&vt[g]     = *(uint4*)&tmp[0];
        *(uint4*)&vt[g + 8] = *(uint4*)&tmp[8];
    }
}

// ---------------------------------------------------------------------------
// bf16 MFMA GEMM (m97 structure), unchanged.
// ---------------------------------------------------------------------------
template <typename OUT>
__global__ __launch_bounds__(256) void gemm_bt(const ushort_t* __restrict__ A,
                                               const ushort_t* __restrict__ Bt,
                                               const float* __restrict__ bias,
                                               OUT* __restrict__ C,
                                               int M, int N, int K)
{
    __shared__ ushort_t As[128 * 32];
    __shared__ ushort_t Bs[128 * 32];
    const int tid = threadIdx.x;
    const int row0 = blockIdx.y * 128, col0 = blockIdx.x * 128;
    const int wid = tid >> 6, lane = tid & 63;
    const int wm = wid >> 1, wn = wid & 1;
    const int quad = lane >> 4, ln = lane & 15;

    f4v acc[4][4] = {};

    const int srow = (lane >> 2);
    const int scol = (lane & 3) * 8;

    for (int k0 = 0; k0 < K; k0 += 32) {
        #pragma unroll
        for (int t = 0; t < 2; t++) {
            int chunk = wid * 2 + t;
            int r = chunk * 16 + srow;
            gld_lds16(&A[(size_t)(row0 + r) * K + k0 + scol], &As[chunk * 512]);
            gld_lds16(&Bt[(size_t)(col0 + r) * K + k0 + scol], &Bs[chunk * 512]);
        }
        __syncthreads();
        s8v af[4], bf[4];
        #pragma unroll
        for (int mt = 0; mt < 4; mt++)
            af[mt] = *(const s8v*)&As[(wm * 64 + mt * 16 + ln) * 32 + quad * 8];
        #pragma unroll
        for (int nt = 0; nt < 4; nt++)
            bf[nt] = *(const s8v*)&Bs[(wn * 64 + nt * 16 + ln) * 32 + quad * 8];
        #pragma unroll
        for (int mt = 0; mt < 4; mt++)
            #pragma unroll
            for (int nt = 0; nt < 4; nt++)
                acc[mt][nt] = __builtin_amdgcn_mfma_f32_16x16x32_bf16(
                    af[mt], bf[nt], acc[mt][nt], 0, 0, 0);
        __syncthreads();
    }

    #pragma unroll
    for (int mt = 0; mt < 4; mt++) {
        #pragma unroll
        for (int nt = 0; nt < 4; nt++) {
            int c = col0 + wn * 64 + nt * 16 + ln;
            float bv = bias[c];
            #pragma unroll
            for (int reg = 0; reg < 4; reg++) {
                int r = row0 + wm * 64 + mt * 16 + quad * 4 + reg;
                float v = acc[mt][nt][reg] + bv;
                if constexpr (sizeof(OUT) == 2)
                    C[(size_t)r * N + c] = (OUT)f2bf(v);
                else
                    C[(size_t)r * N + c] = v;
            }
        }
    }
}

// ---------------------------------------------------------------------------
// Flash v7: v6 per-iter structure + SPLIT-K. Block = (pair p, k-half).
// Fixed-max softmax => O,l partials over disjoint k-ranges sum exactly.
// 1024 blocks x 128 thr (~4/CU co-resident), each 32-33 uniform iters.
// Partials merged via device-scope atomicAdd into fp32 Oacc / lacc.
// ---------------------------------------------------------------------------
__global__ __launch_bounds__(128) void flash_mfma(const ushort_t* __restrict__ qkv,
                                                  const ushort_t* __restrict__ vt,
                                                  float* __restrict__ Oacc,
                                                  float* __restrict__ lacc)
{
    __shared__ ushort_t Ks[64 * 72];   // [kseq][d]
    __shared__ ushort_t Vs[64 * 72];   // [d][kseq]
    __shared__ ushort_t Ps[64 * 72];   // [q][kseq]

    const int p     = blockIdx.x >> 1; // 0..31
    const int khalf = blockIdx.x & 1;
    const int h = blockIdx.y, b = blockIdx.z;
    const int tid = threadIdx.x;
    const int w = tid >> 6, lane = tid & 63;   // w in {0,1}
    const int quad = lane >> 4, ln = lane & 15;

    const int sr = tid >> 1, sc = (tid & 1) * 32;   // staging: 2 threads/row
    const int ldsw = sr * 72 + sc;
    const size_t kstep = (size_t)64 * 3 * DH;
    const float C_EXP = 0.18033688011112042f;  // 0.125 * log2(e)

    const int qts[2] = {63 - p, p};

    for (int ti = 0; ti < 2; ti++) {
        const int qt = qts[ti], q0 = qt * 64;
        const int qrow0 = q0 + w * 32;           // this wave's 32 q-rows
        const int n = qt + 1;                    // kt tiles in this row-block
        const int ktBeg = khalf ? ((n + 1) >> 1) : 0;
        const int ktEnd = khalf ? n : ((n + 1) >> 1);

        // Q B-frags for both q-groups, loop-invariant, direct from global
        s8v qa[2][2];
        #pragma unroll
        for (int qg = 0; qg < 2; qg++) {
            const ushort_t* qrow = qkv
                + ((size_t)(b * LSEQ + qrow0 + qg * 16 + ln)) * (3 * DH) + h * HDIM;
            qa[qg][0] = *(const s8v*)(qrow + quad * 8);
            qa[qg][1] = *(const s8v*)(qrow + 32 + quad * 8);
        }

        float l_s[2] = {0.0f, 0.0f};
        f4v o_acc[2][4] = {};

        size_t gk = ((size_t)(b * LSEQ + ktBeg * 64 + sr)) * (3 * DH) + DH + h * HDIM + sc;
        size_t gv = ((size_t)((b * NH + h) * 64 + sr)) * LSEQ + ktBeg * 64 + sc;
        uint4 pk0 = *(const uint4*)&qkv[gk];
        uint4 pk1 = *(const uint4*)&qkv[gk + 8];
        uint4 pk2 = *(const uint4*)&qkv[gk + 16];
        uint4 pk3 = *(const uint4*)&qkv[gk + 24];
        uint4 pv0 = *(const uint4*)&vt[gv];
        uint4 pv1 = *(const uint4*)&vt[gv + 8];
        uint4 pv2 = *(const uint4*)&vt[gv + 16];
        uint4 pv3 = *(const uint4*)&vt[gv + 24];

        for (int kt = ktBeg; kt < ktEnd; kt++) {
            const int k0 = kt * 64;
            __syncthreads();   // all waves done reading prev Ks/Vs
            *(uint4*)&Ks[ldsw]      = pk0;
            *(uint4*)&Ks[ldsw + 8]  = pk1;
            *(uint4*)&Ks[ldsw + 16] = pk2;
            *(uint4*)&Ks[ldsw + 24] = pk3;
            *(uint4*)&Vs[ldsw]      = pv0;
            *(uint4*)&Vs[ldsw + 8]  = pv1;
            *(uint4*)&Vs[ldsw + 16] = pv2;
            *(uint4*)&Vs[ldsw + 24] = pv3;
            if (kt + 1 < ktEnd) {
                gk += kstep; gv += 64;
                pk0 = *(const uint4*)&qkv[gk];
                pk1 = *(const uint4*)&qkv[gk + 8];
                pk2 = *(const uint4*)&qkv[gk + 16];
                pk3 = *(const uint4*)&qkv[gk + 24];
                pv0 = *(const uint4*)&vt[gv];
                pv1 = *(const uint4*)&vt[gv + 8];
                pv2 = *(const uint4*)&vt[gv + 16];
                pv3 = *(const uint4*)&vt[gv + 24];
            }
            __syncthreads();

            // shared fragments: full K tile + full V tile, read ONCE per wave
            s8v kb[4][2], vb[4][2];
            #pragma unroll
            for (int nt = 0; nt < 4; nt++) {
                kb[nt][0] = *(const s8v*)&Ks[(nt * 16 + ln) * 72 + quad * 8];
                kb[nt][1] = *(const s8v*)&Ks[(nt * 16 + ln) * 72 + 32 + quad * 8];
            }
            #pragma unroll
            for (int dt = 0; dt < 4; dt++) {
                vb[dt][0] = *(const s8v*)&Vs[(dt * 16 + ln) * 72 + quad * 8];
                vb[dt][1] = *(const s8v*)&Vs[(dt * 16 + ln) * 72 + 32 + quad * 8];
            }

            #pragma unroll
            for (int qg = 0; qg < 2; qg++) {
                // S^T[k0+nt*16+quad*4+reg][qrow0+qg*16+ln]
                f4v s[4] = {};
                #pragma unroll
                for (int nt = 0; nt < 4; nt++) {
                    s[nt] = __builtin_amdgcn_mfma_f32_16x16x32_bf16(kb[nt][0], qa[qg][0], s[nt], 0, 0, 0);
                    s[nt] = __builtin_amdgcn_mfma_f32_16x16x32_bf16(kb[nt][1], qa[qg][1], s[nt], 0, 0, 0);
                }

                float pp[4][4];
                const int q = qrow0 + qg * 16 + ln;
                if (kt == qt) {
                    #pragma unroll
                    for (int nt = 0; nt < 4; nt++) {
                        #pragma unroll
                        for (int reg = 0; reg < 4; reg++) {
                            int kidx = k0 + nt * 16 + quad * 4 + reg;
                            bool valid = (kidx <= q) && (kidx >= 1 || q == 0);
                            pp[nt][reg] = valid ? __builtin_amdgcn_exp2f(s[nt][reg] * C_EXP) : 0.0f;
                        }
                    }
                } else {
                    #pragma unroll
                    for (int nt = 0; nt < 4; nt++)
                        #pragma unroll
                        for (int reg = 0; reg < 4; reg++)
                            pp[nt][reg] = __builtin_amdgcn_exp2f(s[nt][reg] * C_EXP);
                    if (kt == 0 && quad == 0)   // k==0 invalid (q >= 64 in this branch)
                        pp[0][0] = 0.0f;
                }

                #pragma unroll
                for (int nt = 0; nt < 4; nt++)
                    l_s[qg] += (pp[nt][0] + pp[nt][1]) + (pp[nt][2] + pp[nt][3]);

                const int prow = (w * 32 + qg * 16 + ln) * 72;
                #pragma unroll
                for (int nt = 0; nt < 4; nt++) {
                    unsigned int lo = (unsigned int)f2bf(pp[nt][0]) | ((unsigned int)f2bf(pp[nt][1]) << 16);
                    unsigned int hi = (unsigned int)f2bf(pp[nt][2]) | ((unsigned int)f2bf(pp[nt][3]) << 16);
                    uint2 pkd; pkd.x = lo; pkd.y = hi;
                    *(uint2*)&Ps[prow + nt * 16 + quad * 4] = pkd;
                }
                // wave-private rows: no barrier

                s8v pa0 = *(const s8v*)&Ps[prow + quad * 8];
                s8v pa1 = *(const s8v*)&Ps[prow + 32 + quad * 8];
                #pragma unroll
                for (int dt = 0; dt < 4; dt++) {
                    o_acc[qg][dt] = __builtin_amdgcn_mfma_f32_16x16x32_bf16(pa0, vb[dt][0], o_acc[qg][dt], 0, 0, 0);
                    o_acc[qg][dt] = __builtin_amdgcn_mfma_f32_16x16x32_bf16(pa1, vb[dt][1], o_acc[qg][dt], 0, 0, 0);
                }
            }
        }

        // merge partials (device-scope atomics; each address touched by 2 blocks)
        #pragma unroll
        for (int qg = 0; qg < 2; qg++) {
            float lf = l_s[qg];
            lf += __shfl_xor(lf, 16);
            lf += __shfl_xor(lf, 32);
            if (quad == 0)
                atomicAdd(&lacc[((size_t)(b * NH + h)) * LSEQ + qrow0 + qg * 16 + ln], lf);
            #pragma unroll
            for (int dt = 0; dt < 4; dt++)
                #pragma unroll
                for (int reg = 0; reg < 4; reg++)
                    atomicAdd(&Oacc[((size_t)(b * LSEQ + qrow0 + qg * 16 + quad * 4 + reg)) * DH
                                    + h * HDIM + dt * 16 + ln],
                              o_acc[qg][dt][reg]);
        }
    }
}

// ---------------------------------------------------------------------------
// att[b,l,h*64+d] = Oacc / lacc  (fp32 -> bf16). 16 elems/thread.
// ---------------------------------------------------------------------------
__global__ __launch_bounds__(256) void normalize(const float* __restrict__ Oacc,
                                                 const float* __restrict__ lacc,
                                                 ushort_t* __restrict__ att)
{
    int t = blockIdx.x * 256 + threadIdx.x;   // 262144 threads
    int row = t >> 5;                          // 0..8191
    int col0 = (t & 31) * 16;
    int h = col0 >> 6;
    int b = row >> 12, l = row & (LSEQ - 1);
    float linv = 1.0f / lacc[((size_t)(b * NH + h)) * LSEQ + l];
    const float* o = &Oacc[(size_t)row * DH + col0];
    ushort_t tmp[16];
    #pragma unroll
    for (int j = 0; j < 16; j++) tmp[j] = f2bf(o[j] * linv);
    size_t g = (size_t)row * DH + col0;
    *(uint4*)&att[g]     = *(uint4*)&tmp[0];
    *(uint4*)&att[g + 8] = *(uint4*)&tmp[8];
}

// ---------------------------------------------------------------------------
extern "C" void kernel_launch(void* const* d_in, const int* in_sizes, int n_in,
                              void* d_out, int out_size, void* d_ws, size_t ws_size,
                              hipStream_t stream)
{
    const float* x     = (const float*)d_in[0];  // [2,4096,512]
    const float* w_in  = (const float*)d_in[1];  // [512,1536]
    const float* b_in  = (const float*)d_in[2];  // [1536]
    const float* w_out = (const float*)d_in[3];  // [512,512]
    const float* b_out = (const float*)d_in[4];  // [512]
    float* out = (float*)d_out;                  // [2,4096,512] fp32

    const int M = BSZ * LSEQ;                    // 8192
    char* ws = (char*)d_ws;
    ushort_t* xb    = (ushort_t*)ws;                       ws += (size_t)M * DH * 2;        // 8.4MB
    ushort_t* w_inT = (ushort_t*)ws;                       ws += (size_t)3 * DH * DH * 2;   // 1.6MB
    ushort_t* w_outT= (ushort_t*)ws;                       ws += (size_t)DH * DH * 2;       // 0.5MB
    ushort_t* qkvb  = (ushort_t*)ws;                       ws += (size_t)M * 3 * DH * 2;    // 25.2MB
    ushort_t* vtb   = (ushort_t*)ws;                       ws += (size_t)M * DH * 2;        // 8.4MB
    ushort_t* attb  = (ushort_t*)ws;                       ws += (size_t)M * DH * 2;        // 8.4MB
    float*    Oacc  = (float*)ws;                          ws += (size_t)M * DH * 4;        // 16.8MB
    float*    lacc  = (float*)ws;                          /* 256KB */

    prep<<<9280, 256, 0, stream>>>(x, xb, w_in, w_inT, w_out, w_outT, Oacc, lacc);

    gemm_bt<ushort_t><<<dim3(3 * DH / 128, M / 128), 256, 0, stream>>>(
        xb, w_inT, b_in, qkvb, M, 3 * DH, DH);

    vtrans<<<dim3(LSEQ / 64, NH, BSZ), 256, 0, stream>>>(qkvb, vtb);

    flash_mfma<<<dim3(64, NH, BSZ), 128, 0, stream>>>(qkvb, vtb, Oacc, lacc);

    normalize<<<1024, 256, 0, stream>>>(Oacc, lacc, attb);

    gemm_bt<float><<<dim3(DH / 128, M / 128), 256, 0, stream>>>(
        attb, w_outT, b_out, out, M, DH, DH);
}

// Round 11
// 189.605 us; speedup vs baseline: 1.1144x; 1.0264x over previous
//
#include <hip/hip_runtime.h>
#include <hip/hip_bf16.h>

#define BSZ   2
#define LSEQ  4096
#define DH    512
#define NH    8
#define HDIM  64

typedef unsigned short ushort_t;
typedef __attribute__((ext_vector_type(8))) short s8v;    // 8 bf16 = 4 VGPRs
typedef __attribute__((ext_vector_type(4))) short s4v;    // 4 bf16 = 2 VGPRs
typedef __attribute__((ext_vector_type(4))) float f4v;    // MFMA accumulator

#define C_EXP 0.18033688011112042f   // 0.125 * log2(e)

__device__ __forceinline__ ushort_t f2bf(float f) {
    __hip_bfloat16 h = __float2bfloat16(f);
    return *(ushort_t*)&h;
}

// async global->LDS, 16B per lane; LDS dest = wave-uniform base + lane*16B
__device__ __forceinline__ void gld_lds16(const ushort_t* g, ushort_t* l) {
    __builtin_amdgcn_global_load_lds(
        (const __attribute__((address_space(1))) void*)g,
        (__attribute__((address_space(3))) void*)l, 16, 0, 0);
}

// ---------------------------------------------------------------------------
// Fused prep: cast x->bf16, transpose both weights, zero O/l accumulators.
// ---------------------------------------------------------------------------
__device__ __forceinline__ void transpose_tile(const float* __restrict__ src,
                                               ushort_t* __restrict__ dst,
                                               int R, int C, int bx, int by)
{
    __shared__ float tile[32][33];
    int r0 = by * 32, c0 = bx * 32;
    int t = threadIdx.x;
    int tr = t >> 5, tc = t & 31;
    #pragma unroll
    for (int i = 0; i < 4; i++)
        tile[tr + 8 * i][tc] = src[(size_t)(r0 + tr + 8 * i) * C + c0 + tc];
    __syncthreads();
    #pragma unroll
    for (int i = 0; i < 4; i++) {
        int oc = tr + 8 * i;
        dst[(size_t)(c0 + oc) * R + r0 + tc] = f2bf(tile[tc][oc]);
    }
}

__global__ __launch_bounds__(256) void prep(const float* __restrict__ x,
                                            ushort_t* __restrict__ xb,
                                            const float* __restrict__ w_in,
                                            ushort_t* __restrict__ w_inT,
                                            const float* __restrict__ w_out,
                                            ushort_t* __restrict__ w_outT,
                                            float* __restrict__ Oacc,
                                            float* __restrict__ lacc)
{
    int bx = blockIdx.x;
    if (bx < 4096) {
        int i = (bx * 256 + threadIdx.x) * 4;
        float4 v = *(const float4*)&x[i];
        ushort_t o[4] = {f2bf(v.x), f2bf(v.y), f2bf(v.z), f2bf(v.w)};
        *(uint2*)&xb[i] = *(uint2*)o;
    } else if (bx < 4864) {
        int idx = bx - 4096;                     // w_in: [512][1536] -> [1536][512]
        transpose_tile(w_in, w_inT, DH, 3 * DH, idx % 48, idx / 48);
    } else if (bx < 5120) {
        int idx = bx - 4864;                     // w_out: [512][512]
        transpose_tile(w_out, w_outT, DH, DH, idx % 16, idx / 16);
    } else if (bx < 9216) {
        int i = ((bx - 5120) * 256 + threadIdx.x) * 4;   // zero Oacc
        float4 z = {0.f, 0.f, 0.f, 0.f};
        *(float4*)&Oacc[i] = z;
    } else {
        int i = ((bx - 9216) * 256 + threadIdx.x) * 4;   // zero lacc
        float4 z = {0.f, 0.f, 0.f, 0.f};
        *(float4*)&lacc[i] = z;
    }
}

// ---------------------------------------------------------------------------
// bf16 MFMA GEMM (m97 structure). QSCALE: multiply cols<512 by C_EXP (folds
// softmax scale into Q). VTRANS: cols>=1024 (V) are written ONLY transposed
// into vtout[b*NH+h][d][l] (8B packed stores), skipping the C store.
// ---------------------------------------------------------------------------
template <typename OUT, bool QSCALE, bool VTRANS>
__global__ __launch_bounds__(256) void gemm_bt(const ushort_t* __restrict__ A,
                                               const ushort_t* __restrict__ Bt,
                                               const float* __restrict__ bias,
                                               OUT* __restrict__ C,
                                               ushort_t* __restrict__ vtout,
                                               int M, int N, int K)
{
    __shared__ ushort_t As[128 * 32];
    __shared__ ushort_t Bs[128 * 32];
    const int tid = threadIdx.x;
    const int row0 = blockIdx.y * 128, col0 = blockIdx.x * 128;
    const int wid = tid >> 6, lane = tid & 63;
    const int wm = wid >> 1, wn = wid & 1;
    const int quad = lane >> 4, ln = lane & 15;

    f4v acc[4][4] = {};

    const int srow = (lane >> 2);
    const int scol = (lane & 3) * 8;

    for (int k0 = 0; k0 < K; k0 += 32) {
        #pragma unroll
        for (int t = 0; t < 2; t++) {
            int chunk = wid * 2 + t;
            int r = chunk * 16 + srow;
            gld_lds16(&A[(size_t)(row0 + r) * K + k0 + scol], &As[chunk * 512]);
            gld_lds16(&Bt[(size_t)(col0 + r) * K + k0 + scol], &Bs[chunk * 512]);
        }
        __syncthreads();
        s8v af[4], bf[4];
        #pragma unroll
        for (int mt = 0; mt < 4; mt++)
            af[mt] = *(const s8v*)&As[(wm * 64 + mt * 16 + ln) * 32 + quad * 8];
        #pragma unroll
        for (int nt = 0; nt < 4; nt++)
            bf[nt] = *(const s8v*)&Bs[(wn * 64 + nt * 16 + ln) * 32 + quad * 8];
        #pragma unroll
        for (int mt = 0; mt < 4; mt++)
            #pragma unroll
            for (int nt = 0; nt < 4; nt++)
                acc[mt][nt] = __builtin_amdgcn_mfma_f32_16x16x32_bf16(
                    af[mt], bf[nt], acc[mt][nt], 0, 0, 0);
        __syncthreads();
    }

    #pragma unroll
    for (int mt = 0; mt < 4; mt++) {
        #pragma unroll
        for (int nt = 0; nt < 4; nt++) {
            int c = col0 + wn * 64 + nt * 16 + ln;
            float bv = bias[c];
            float scl = 1.0f;
            if constexpr (QSCALE) scl = (c < DH) ? C_EXP : 1.0f;
            bool vcol = false;
            if constexpr (VTRANS) vcol = (c >= 2 * DH);
            if (vcol) {
                // transposed V store: vt[(b*NH+h)*64 + d][l], 4 contiguous l
                int d = c - 2 * DH;
                int hh = d >> 6, dd = d & 63;
                int r0 = row0 + wm * 64 + mt * 16 + quad * 4;
                int bb = r0 >> 12, l = r0 & (LSEQ - 1);
                ushort_t tmp[4];
                #pragma unroll
                for (int reg = 0; reg < 4; reg++)
                    tmp[reg] = f2bf(acc[mt][nt][reg] + bv);
                *(uint2*)&vtout[((size_t)((bb * NH + hh) * 64 + dd)) * LSEQ + l]
                    = *(uint2*)tmp;
            } else {
                #pragma unroll
                for (int reg = 0; reg < 4; reg++) {
                    int r = row0 + wm * 64 + mt * 16 + quad * 4 + reg;
                    float v = (acc[mt][nt][reg] + bv) * scl;
                    if constexpr (sizeof(OUT) == 2)
                        C[(size_t)r * N + c] = (OUT)f2bf(v);
                    else
                        C[(size_t)r * N + c] = v;
                }
            }
        }
    }
}

// ---------------------------------------------------------------------------
// Flash v8: split-k (block = pair p x k-half) + register-resident P.
// S^T = K@Q^T via 16x16x32; its C-layout (lane: k=quad*4+reg, q=ln) is the
// A/B layout of mfma_f32_16x16x16bf16_1k, so PV consumes P straight from
// VGPRs -> no P LDS round-trip, no Ps buffer (LDS 18.4 KB). Q is pre-scaled
// by 0.125*log2e in the qkv GEMM -> p = exp2(s) directly.
// ---------------------------------------------------------------------------
__global__ __launch_bounds__(128) void flash_mfma(const ushort_t* __restrict__ qkv,
                                                  const ushort_t* __restrict__ vt,
                                                  float* __restrict__ Oacc,
                                                  float* __restrict__ lacc)
{
    __shared__ ushort_t Ks[64 * 72];   // [kseq][d]
    __shared__ ushort_t Vs[64 * 72];   // [d][kseq]

    const int p     = blockIdx.x >> 1; // 0..31
    const int khalf = blockIdx.x & 1;
    const int h = blockIdx.y, b = blockIdx.z;
    const int tid = threadIdx.x;
    const int w = tid >> 6, lane = tid & 63;   // w in {0,1}
    const int quad = lane >> 4, ln = lane & 15;

    const int sr = tid >> 1, sc = (tid & 1) * 32;   // staging: 2 threads/row
    const int ldsw = sr * 72 + sc;
    const size_t kstep = (size_t)64 * 3 * DH;

    const int qts[2] = {63 - p, p};

    for (int ti = 0; ti < 2; ti++) {
        const int qt = qts[ti], q0 = qt * 64;
        const int qrow0 = q0 + w * 32;           // this wave's 32 q-rows
        const int n = qt + 1;
        const int ktBeg = khalf ? ((n + 1) >> 1) : 0;
        const int ktEnd = khalf ? n : ((n + 1) >> 1);

        // Q B-frags (pre-scaled by C_EXP), loop-invariant, from global
        s8v qa[2][2];
        #pragma unroll
        for (int qg = 0; qg < 2; qg++) {
            const ushort_t* qrow = qkv
                + ((size_t)(b * LSEQ + qrow0 + qg * 16 + ln)) * (3 * DH) + h * HDIM;
            qa[qg][0] = *(const s8v*)(qrow + quad * 8);
            qa[qg][1] = *(const s8v*)(qrow + 32 + quad * 8);
        }

        float l_s[2] = {0.0f, 0.0f};
        f4v o_acc[2][4] = {};

        if (ktBeg < ktEnd) {
            size_t gk = ((size_t)(b * LSEQ + ktBeg * 64 + sr)) * (3 * DH) + DH + h * HDIM + sc;
            size_t gv = ((size_t)((b * NH + h) * 64 + sr)) * LSEQ + ktBeg * 64 + sc;
            uint4 pk0 = *(const uint4*)&qkv[gk];
            uint4 pk1 = *(const uint4*)&qkv[gk + 8];
            uint4 pk2 = *(const uint4*)&qkv[gk + 16];
            uint4 pk3 = *(const uint4*)&qkv[gk + 24];
            uint4 pv0 = *(const uint4*)&vt[gv];
            uint4 pv1 = *(const uint4*)&vt[gv + 8];
            uint4 pv2 = *(const uint4*)&vt[gv + 16];
            uint4 pv3 = *(const uint4*)&vt[gv + 24];

            for (int kt = ktBeg; kt < ktEnd; kt++) {
                const int k0 = kt * 64;
                __syncthreads();   // all waves done reading prev Ks/Vs
                *(uint4*)&Ks[ldsw]      = pk0;
                *(uint4*)&Ks[ldsw + 8]  = pk1;
                *(uint4*)&Ks[ldsw + 16] = pk2;
                *(uint4*)&Ks[ldsw + 24] = pk3;
                *(uint4*)&Vs[ldsw]      = pv0;
                *(uint4*)&Vs[ldsw + 8]  = pv1;
                *(uint4*)&Vs[ldsw + 16] = pv2;
                *(uint4*)&Vs[ldsw + 24] = pv3;
                if (kt + 1 < ktEnd) {
                    gk += kstep; gv += 64;
                    pk0 = *(const uint4*)&qkv[gk];
                    pk1 = *(const uint4*)&qkv[gk + 8];
                    pk2 = *(const uint4*)&qkv[gk + 16];
                    pk3 = *(const uint4*)&qkv[gk + 24];
                    pv0 = *(const uint4*)&vt[gv];
                    pv1 = *(const uint4*)&vt[gv + 8];
                    pv2 = *(const uint4*)&vt[gv + 16];
                    pv3 = *(const uint4*)&vt[gv + 24];
                }
                __syncthreads();

                // K frags (b128) + V frags (b64 per 16-k chunk), read once
                s8v kb[4][2];
                #pragma unroll
                for (int nt = 0; nt < 4; nt++) {
                    kb[nt][0] = *(const s8v*)&Ks[(nt * 16 + ln) * 72 + quad * 8];
                    kb[nt][1] = *(const s8v*)&Ks[(nt * 16 + ln) * 72 + 32 + quad * 8];
                }
                s4v vf[4][4];   // [dt][chunk]
                #pragma unroll
                for (int dt = 0; dt < 4; dt++)
                    #pragma unroll
                    for (int nt = 0; nt < 4; nt++)
                        vf[dt][nt] = *(const s4v*)&Vs[(dt * 16 + ln) * 72 + nt * 16 + quad * 4];

                #pragma unroll
                for (int qg = 0; qg < 2; qg++) {
                    // S^T[k0+nt*16+quad*4+reg][qrow0+qg*16+ln]
                    f4v s[4] = {};
                    #pragma unroll
                    for (int nt = 0; nt < 4; nt++) {
                        s[nt] = __builtin_amdgcn_mfma_f32_16x16x32_bf16(kb[nt][0], qa[qg][0], s[nt], 0, 0, 0);
                        s[nt] = __builtin_amdgcn_mfma_f32_16x16x32_bf16(kb[nt][1], qa[qg][1], s[nt], 0, 0, 0);
                    }

                    float pp[4][4];
                    const int q = qrow0 + qg * 16 + ln;
                    if (kt == qt) {
                        #pragma unroll
                        for (int nt = 0; nt < 4; nt++) {
                            #pragma unroll
                            for (int reg = 0; reg < 4; reg++) {
                                int kidx = k0 + nt * 16 + quad * 4 + reg;
                                bool valid = (kidx <= q) && (kidx >= 1 || q == 0);
                                pp[nt][reg] = valid ? __builtin_amdgcn_exp2f(s[nt][reg]) : 0.0f;
                            }
                        }
                    } else {
                        #pragma unroll
                        for (int nt = 0; nt < 4; nt++)
                            #pragma unroll
                            for (int reg = 0; reg < 4; reg++)
                                pp[nt][reg] = __builtin_amdgcn_exp2f(s[nt][reg]);
                        if (kt == 0 && quad == 0)   // k==0 invalid (q >= 64 here)
                            pp[0][0] = 0.0f;
                    }

                    #pragma unroll
                    for (int nt = 0; nt < 4; nt++)
                        l_s[qg] += (pp[nt][0] + pp[nt][1]) + (pp[nt][2] + pp[nt][3]);

                    // P stays in registers: A-operand of 16x16x16bf16_1k
                    #pragma unroll
                    for (int nt = 0; nt < 4; nt++) {
                        s4v pf = { (short)f2bf(pp[nt][0]), (short)f2bf(pp[nt][1]),
                                   (short)f2bf(pp[nt][2]), (short)f2bf(pp[nt][3]) };
                        #pragma unroll
                        for (int dt = 0; dt < 4; dt++)
                            o_acc[qg][dt] = __builtin_amdgcn_mfma_f32_16x16x16bf16_1k(
                                pf, vf[dt][nt], o_acc[qg][dt], 0, 0, 0);
                    }
                }
            }
        }

        // merge partials (device-scope atomics; 2 writers per address)
        #pragma unroll
        for (int qg = 0; qg < 2; qg++) {
            float lf = l_s[qg];
            lf += __shfl_xor(lf, 16);
            lf += __shfl_xor(lf, 32);
            if (quad == 0)
                atomicAdd(&lacc[((size_t)(b * NH + h)) * LSEQ + qrow0 + qg * 16 + ln], lf);
            #pragma unroll
            for (int dt = 0; dt < 4; dt++)
                #pragma unroll
                for (int reg = 0; reg < 4; reg++)
                    atomicAdd(&Oacc[((size_t)(b * LSEQ + qrow0 + qg * 16 + quad * 4 + reg)) * DH
                                    + h * HDIM + dt * 16 + ln],
                              o_acc[qg][dt][reg]);
        }
    }
}

// ---------------------------------------------------------------------------
// att[b,l,h*64+d] = Oacc / lacc  (fp32 -> bf16). 16 elems/thread.
// ---------------------------------------------------------------------------
__global__ __launch_bounds__(256) void normalize(const float* __restrict__ Oacc,
                                                 const float* __restrict__ lacc,
                                                 ushort_t* __restrict__ att)
{
    int t = blockIdx.x * 256 + threadIdx.x;   // 262144 threads
    int row = t >> 5;                          // 0..8191
    int col0 = (t & 31) * 16;
    int h = col0 >> 6;
    int b = row >> 12, l = row & (LSEQ - 1);
    float linv = 1.0f / lacc[((size_t)(b * NH + h)) * LSEQ + l];
    const float* o = &Oacc[(size_t)row * DH + col0];
    ushort_t tmp[16];
    #pragma unroll
    for (int j = 0; j < 16; j++) tmp[j] = f2bf(o[j] * linv);
    size_t g = (size_t)row * DH + col0;
    *(uint4*)&att[g]     = *(uint4*)&tmp[0];
    *(uint4*)&att[g + 8] = *(uint4*)&tmp[8];
}

// ---------------------------------------------------------------------------
extern "C" void kernel_launch(void* const* d_in, const int* in_sizes, int n_in,
                              void* d_out, int out_size, void* d_ws, size_t ws_size,
                              hipStream_t stream)
{
    const float* x     = (const float*)d_in[0];  // [2,4096,512]
    const float* w_in  = (const float*)d_in[1];  // [512,1536]
    const float* b_in  = (const float*)d_in[2];  // [1536]
    const float* w_out = (const float*)d_in[3];  // [512,512]
    const float* b_out = (const float*)d_in[4];  // [512]
    float* out = (float*)d_out;                  // [2,4096,512] fp32

    const int M = BSZ * LSEQ;                    // 8192
    char* ws = (char*)d_ws;
    ushort_t* xb    = (ushort_t*)ws;                       ws += (size_t)M * DH * 2;        // 8.4MB
    ushort_t* w_inT = (ushort_t*)ws;                       ws += (size_t)3 * DH * DH * 2;   // 1.6MB
    ushort_t* w_outT= (ushort_t*)ws;                       ws += (size_t)DH * DH * 2;       // 0.5MB
    ushort_t* qkvb  = (ushort_t*)ws;                       ws += (size_t)M * 3 * DH * 2;    // 25.2MB
    ushort_t* vtb   = (ushort_t*)ws;                       ws += (size_t)M * DH * 2;        // 8.4MB
    ushort_t* attb  = (ushort_t*)ws;                       ws += (size_t)M * DH * 2;        // 8.4MB
    float*    Oacc  = (float*)ws;                          ws += (size_t)M * DH * 4;        // 16.8MB
    float*    lacc  = (float*)ws;                          /* 256KB */

    prep<<<9280, 256, 0, stream>>>(x, xb, w_in, w_inT, w_out, w_outT, Oacc, lacc);

    // qkv GEMM: scales Q cols by C_EXP, writes V cols transposed into vtb
    gemm_bt<ushort_t, true, true><<<dim3(3 * DH / 128, M / 128), 256, 0, stream>>>(
        xb, w_inT, b_in, qkvb, vtb, M, 3 * DH, DH);

    flash_mfma<<<dim3(64, NH, BSZ), 128, 0, stream>>>(qkvb, vtb, Oacc, lacc);

    normalize<<<1024, 256, 0, stream>>>(Oacc, lacc, attb);

    gemm_bt<float, false, false><<<dim3(DH / 128, M / 128), 256, 0, stream>>>(
        attb, w_outT, b_out, out, nullptr, M, DH, DH);
}

// Round 12
// 188.194 us; speedup vs baseline: 1.1228x; 1.0075x over previous
//
#include <hip/hip_runtime.h>
#include <hip/hip_bf16.h>

#define BSZ   2
#define LSEQ  4096
#define DH    512
#define NH    8
#define HDIM  64

typedef unsigned short ushort_t;
typedef __attribute__((ext_vector_type(8))) short s8v;    // 8 bf16 = 4 VGPRs
typedef __attribute__((ext_vector_type(4))) short s4v;    // 4 bf16 = 2 VGPRs
typedef __attribute__((ext_vector_type(4))) float f4v;    // MFMA accumulator

#define C_EXP 0.18033688011112042f   // 0.125 * log2(e)

__device__ __forceinline__ ushort_t f2bf(float f) {
    __hip_bfloat16 h = __float2bfloat16(f);
    return *(ushort_t*)&h;
}

__device__ __forceinline__ unsigned int fbits(float f) {
    union { float f; unsigned int u; } c; c.f = f; return c.u;
}

// pack two fp32 into bf16x2 by TRUNCATION (1-2 VALU ops vs ~5/elem RNE).
// Used only for P (softmax numerator): O and l use the same truncated
// values, so the bias cancels in O/l.
__device__ __forceinline__ unsigned int pk_trunc(float lo, float hi) {
    return (fbits(lo) >> 16) | (fbits(hi) & 0xFFFF0000u);
}

// async global->LDS, 16B per lane; LDS dest = wave-uniform base + lane*16B
__device__ __forceinline__ void gld_lds16(const ushort_t* g, ushort_t* l) {
    __builtin_amdgcn_global_load_lds(
        (const __attribute__((address_space(1))) void*)g,
        (__attribute__((address_space(3))) void*)l, 16, 0, 0);
}

// ---------------------------------------------------------------------------
// Fused prep: cast x->bf16, transpose both weights, zero O/l accumulators.
// ---------------------------------------------------------------------------
__device__ __forceinline__ void transpose_tile(const float* __restrict__ src,
                                               ushort_t* __restrict__ dst,
                                               int R, int C, int bx, int by)
{
    __shared__ float tile[32][33];
    int r0 = by * 32, c0 = bx * 32;
    int t = threadIdx.x;
    int tr = t >> 5, tc = t & 31;
    #pragma unroll
    for (int i = 0; i < 4; i++)
        tile[tr + 8 * i][tc] = src[(size_t)(r0 + tr + 8 * i) * C + c0 + tc];
    __syncthreads();
    #pragma unroll
    for (int i = 0; i < 4; i++) {
        int oc = tr + 8 * i;
        dst[(size_t)(c0 + oc) * R + r0 + tc] = f2bf(tile[tc][oc]);
    }
}

__global__ __launch_bounds__(256) void prep(const float* __restrict__ x,
                                            ushort_t* __restrict__ xb,
                                            const float* __restrict__ w_in,
                                            ushort_t* __restrict__ w_inT,
                                            const float* __restrict__ w_out,
                                            ushort_t* __restrict__ w_outT,
                                            float* __restrict__ Oacc,
                                            float* __restrict__ lacc)
{
    int bx = blockIdx.x;
    if (bx < 4096) {
        int i = (bx * 256 + threadIdx.x) * 4;
        float4 v = *(const float4*)&x[i];
        ushort_t o[4] = {f2bf(v.x), f2bf(v.y), f2bf(v.z), f2bf(v.w)};
        *(uint2*)&xb[i] = *(uint2*)o;
    } else if (bx < 4864) {
        int idx = bx - 4096;                     // w_in: [512][1536] -> [1536][512]
        transpose_tile(w_in, w_inT, DH, 3 * DH, idx % 48, idx / 48);
    } else if (bx < 5120) {
        int idx = bx - 4864;                     // w_out: [512][512]
        transpose_tile(w_out, w_outT, DH, DH, idx % 16, idx / 16);
    } else if (bx < 9216) {
        int i = ((bx - 5120) * 256 + threadIdx.x) * 4;   // zero Oacc
        float4 z = {0.f, 0.f, 0.f, 0.f};
        *(float4*)&Oacc[i] = z;
    } else {
        int i = ((bx - 9216) * 256 + threadIdx.x) * 4;   // zero lacc
        float4 z = {0.f, 0.f, 0.f, 0.f};
        *(float4*)&lacc[i] = z;
    }
}

// ---------------------------------------------------------------------------
// bf16 MFMA GEMM (m97 structure). QSCALE: multiply cols<512 by C_EXP (folds
// softmax scale into Q). VTRANS: cols>=1024 (V) are written ONLY transposed
// into vtout[b*NH+h][d][l] (8B packed stores), skipping the C store.
// ---------------------------------------------------------------------------
template <typename OUT, bool QSCALE, bool VTRANS>
__global__ __launch_bounds__(256) void gemm_bt(const ushort_t* __restrict__ A,
                                               const ushort_t* __restrict__ Bt,
                                               const float* __restrict__ bias,
                                               OUT* __restrict__ C,
                                               ushort_t* __restrict__ vtout,
                                               int M, int N, int K)
{
    __shared__ ushort_t As[128 * 32];
    __shared__ ushort_t Bs[128 * 32];
    const int tid = threadIdx.x;
    const int row0 = blockIdx.y * 128, col0 = blockIdx.x * 128;
    const int wid = tid >> 6, lane = tid & 63;
    const int wm = wid >> 1, wn = wid & 1;
    const int quad = lane >> 4, ln = lane & 15;

    f4v acc[4][4] = {};

    const int srow = (lane >> 2);
    const int scol = (lane & 3) * 8;

    for (int k0 = 0; k0 < K; k0 += 32) {
        #pragma unroll
        for (int t = 0; t < 2; t++) {
            int chunk = wid * 2 + t;
            int r = chunk * 16 + srow;
            gld_lds16(&A[(size_t)(row0 + r) * K + k0 + scol], &As[chunk * 512]);
            gld_lds16(&Bt[(size_t)(col0 + r) * K + k0 + scol], &Bs[chunk * 512]);
        }
        __syncthreads();
        s8v af[4], bf[4];
        #pragma unroll
        for (int mt = 0; mt < 4; mt++)
            af[mt] = *(const s8v*)&As[(wm * 64 + mt * 16 + ln) * 32 + quad * 8];
        #pragma unroll
        for (int nt = 0; nt < 4; nt++)
            bf[nt] = *(const s8v*)&Bs[(wn * 64 + nt * 16 + ln) * 32 + quad * 8];
        #pragma unroll
        for (int mt = 0; mt < 4; mt++)
            #pragma unroll
            for (int nt = 0; nt < 4; nt++)
                acc[mt][nt] = __builtin_amdgcn_mfma_f32_16x16x32_bf16(
                    af[mt], bf[nt], acc[mt][nt], 0, 0, 0);
        __syncthreads();
    }

    #pragma unroll
    for (int mt = 0; mt < 4; mt++) {
        #pragma unroll
        for (int nt = 0; nt < 4; nt++) {
            int c = col0 + wn * 64 + nt * 16 + ln;
            float bv = bias[c];
            float scl = 1.0f;
            if constexpr (QSCALE) scl = (c < DH) ? C_EXP : 1.0f;
            bool vcol = false;
            if constexpr (VTRANS) vcol = (c >= 2 * DH);
            if (vcol) {
                // transposed V store: vt[(b*NH+h)*64 + d][l], 4 contiguous l
                int d = c - 2 * DH;
                int hh = d >> 6, dd = d & 63;
                int r0 = row0 + wm * 64 + mt * 16 + quad * 4;
                int bb = r0 >> 12, l = r0 & (LSEQ - 1);
                ushort_t tmp[4];
                #pragma unroll
                for (int reg = 0; reg < 4; reg++)
                    tmp[reg] = f2bf(acc[mt][nt][reg] + bv);
                *(uint2*)&vtout[((size_t)((bb * NH + hh) * 64 + dd)) * LSEQ + l]
                    = *(uint2*)tmp;
            } else {
                #pragma unroll
                for (int reg = 0; reg < 4; reg++) {
                    int r = row0 + wm * 64 + mt * 16 + quad * 4 + reg;
                    float v = (acc[mt][nt][reg] + bv) * scl;
                    if constexpr (sizeof(OUT) == 2)
                        C[(size_t)r * N + c] = (OUT)f2bf(v);
                    else
                        C[(size_t)r * N + c] = v;
                }
            }
        }
    }
}

// ---------------------------------------------------------------------------
// Flash v9: v8 (split-k, register-resident P via 16x16x16bf16_1k) with
// TRUNCATION-packed P: 2 cheap pack insts per 4 values instead of ~20
// software-RNE ops (gfx950 has no HW bf16 cvt). O and l both use the
// truncated P, so the bias cancels in O/l.
// ---------------------------------------------------------------------------
__global__ __launch_bounds__(128) void flash_mfma(const ushort_t* __restrict__ qkv,
                                                  const ushort_t* __restrict__ vt,
                                                  float* __restrict__ Oacc,
                                                  float* __restrict__ lacc)
{
    __shared__ ushort_t Ks[64 * 72];   // [kseq][d]
    __shared__ ushort_t Vs[64 * 72];   // [d][kseq]

    const int p     = blockIdx.x >> 1; // 0..31
    const int khalf = blockIdx.x & 1;
    const int h = blockIdx.y, b = blockIdx.z;
    const int tid = threadIdx.x;
    const int w = tid >> 6, lane = tid & 63;   // w in {0,1}
    const int quad = lane >> 4, ln = lane & 15;

    const int sr = tid >> 1, sc = (tid & 1) * 32;   // staging: 2 threads/row
    const int ldsw = sr * 72 + sc;
    const size_t kstep = (size_t)64 * 3 * DH;

    const int qts[2] = {63 - p, p};

    for (int ti = 0; ti < 2; ti++) {
        const int qt = qts[ti], q0 = qt * 64;
        const int qrow0 = q0 + w * 32;           // this wave's 32 q-rows
        const int n = qt + 1;
        const int ktBeg = khalf ? ((n + 1) >> 1) : 0;
        const int ktEnd = khalf ? n : ((n + 1) >> 1);

        // Q B-frags (pre-scaled by C_EXP), loop-invariant, from global
        s8v qa[2][2];
        #pragma unroll
        for (int qg = 0; qg < 2; qg++) {
            const ushort_t* qrow = qkv
                + ((size_t)(b * LSEQ + qrow0 + qg * 16 + ln)) * (3 * DH) + h * HDIM;
            qa[qg][0] = *(const s8v*)(qrow + quad * 8);
            qa[qg][1] = *(const s8v*)(qrow + 32 + quad * 8);
        }

        float l_s[2] = {0.0f, 0.0f};
        f4v o_acc[2][4] = {};

        if (ktBeg < ktEnd) {
            size_t gk = ((size_t)(b * LSEQ + ktBeg * 64 + sr)) * (3 * DH) + DH + h * HDIM + sc;
            size_t gv = ((size_t)((b * NH + h) * 64 + sr)) * LSEQ + ktBeg * 64 + sc;
            uint4 pk0 = *(const uint4*)&qkv[gk];
            uint4 pk1 = *(const uint4*)&qkv[gk + 8];
            uint4 pk2 = *(const uint4*)&qkv[gk + 16];
            uint4 pk3 = *(const uint4*)&qkv[gk + 24];
            uint4 pv0 = *(const uint4*)&vt[gv];
            uint4 pv1 = *(const uint4*)&vt[gv + 8];
            uint4 pv2 = *(const uint4*)&vt[gv + 16];
            uint4 pv3 = *(const uint4*)&vt[gv + 24];

            for (int kt = ktBeg; kt < ktEnd; kt++) {
                const int k0 = kt * 64;
                __syncthreads();   // all waves done reading prev Ks/Vs
                *(uint4*)&Ks[ldsw]      = pk0;
                *(uint4*)&Ks[ldsw + 8]  = pk1;
                *(uint4*)&Ks[ldsw + 16] = pk2;
                *(uint4*)&Ks[ldsw + 24] = pk3;
                *(uint4*)&Vs[ldsw]      = pv0;
                *(uint4*)&Vs[ldsw + 8]  = pv1;
                *(uint4*)&Vs[ldsw + 16] = pv2;
                *(uint4*)&Vs[ldsw + 24] = pv3;
                if (kt + 1 < ktEnd) {
                    gk += kstep; gv += 64;
                    pk0 = *(const uint4*)&qkv[gk];
                    pk1 = *(const uint4*)&qkv[gk + 8];
                    pk2 = *(const uint4*)&qkv[gk + 16];
                    pk3 = *(const uint4*)&qkv[gk + 24];
                    pv0 = *(const uint4*)&vt[gv];
                    pv1 = *(const uint4*)&vt[gv + 8];
                    pv2 = *(const uint4*)&vt[gv + 16];
                    pv3 = *(const uint4*)&vt[gv + 24];
                }
                __syncthreads();

                // K frags (b128) + V frags (b64 per 16-k chunk), read once
                s8v kb[4][2];
                #pragma unroll
                for (int nt = 0; nt < 4; nt++) {
                    kb[nt][0] = *(const s8v*)&Ks[(nt * 16 + ln) * 72 + quad * 8];
                    kb[nt][1] = *(const s8v*)&Ks[(nt * 16 + ln) * 72 + 32 + quad * 8];
                }
                s4v vf[4][4];   // [dt][chunk]
                #pragma unroll
                for (int dt = 0; dt < 4; dt++)
                    #pragma unroll
                    for (int nt = 0; nt < 4; nt++)
                        vf[dt][nt] = *(const s4v*)&Vs[(dt * 16 + ln) * 72 + nt * 16 + quad * 4];

                #pragma unroll
                for (int qg = 0; qg < 2; qg++) {
                    // S^T[k0+nt*16+quad*4+reg][qrow0+qg*16+ln]
                    f4v s[4] = {};
                    #pragma unroll
                    for (int nt = 0; nt < 4; nt++) {
                        s[nt] = __builtin_amdgcn_mfma_f32_16x16x32_bf16(kb[nt][0], qa[qg][0], s[nt], 0, 0, 0);
                        s[nt] = __builtin_amdgcn_mfma_f32_16x16x32_bf16(kb[nt][1], qa[qg][1], s[nt], 0, 0, 0);
                    }

                    float pp[4][4];
                    const int q = qrow0 + qg * 16 + ln;
                    if (kt == qt) {
                        #pragma unroll
                        for (int nt = 0; nt < 4; nt++) {
                            #pragma unroll
                            for (int reg = 0; reg < 4; reg++) {
                                int kidx = k0 + nt * 16 + quad * 4 + reg;
                                bool valid = (kidx <= q) && (kidx >= 1 || q == 0);
                                pp[nt][reg] = valid ? __builtin_amdgcn_exp2f(s[nt][reg]) : 0.0f;
                            }
                        }
                    } else {
                        #pragma unroll
                        for (int nt = 0; nt < 4; nt++)
                            #pragma unroll
                            for (int reg = 0; reg < 4; reg++)
                                pp[nt][reg] = __builtin_amdgcn_exp2f(s[nt][reg]);
                        if (kt == 0 && quad == 0)   // k==0 invalid (q >= 64 here)
                            pp[0][0] = 0.0f;
                    }

                    #pragma unroll
                    for (int nt = 0; nt < 4; nt++)
                        l_s[qg] += (pp[nt][0] + pp[nt][1]) + (pp[nt][2] + pp[nt][3]);

                    // P stays in registers: truncation-packed bf16 A-operand
                    #pragma unroll
                    for (int nt = 0; nt < 4; nt++) {
                        union { unsigned int u[2]; s4v v; } pk;
                        pk.u[0] = pk_trunc(pp[nt][0], pp[nt][1]);
                        pk.u[1] = pk_trunc(pp[nt][2], pp[nt][3]);
                        #pragma unroll
                        for (int dt = 0; dt < 4; dt++)
                            o_acc[qg][dt] = __builtin_amdgcn_mfma_f32_16x16x16bf16_1k(
                                pk.v, vf[dt][nt], o_acc[qg][dt], 0, 0, 0);
                    }
                }
            }
        }

        // merge partials (device-scope atomics; 2 writers per address)
        #pragma unroll
        for (int qg = 0; qg < 2; qg++) {
            float lf = l_s[qg];
            lf += __shfl_xor(lf, 16);
            lf += __shfl_xor(lf, 32);
            if (quad == 0)
                atomicAdd(&lacc[((size_t)(b * NH + h)) * LSEQ + qrow0 + qg * 16 + ln], lf);
            #pragma unroll
            for (int dt = 0; dt < 4; dt++)
                #pragma unroll
                for (int reg = 0; reg < 4; reg++)
                    atomicAdd(&Oacc[((size_t)(b * LSEQ + qrow0 + qg * 16 + quad * 4 + reg)) * DH
                                    + h * HDIM + dt * 16 + ln],
                              o_acc[qg][dt][reg]);
        }
    }
}

// ---------------------------------------------------------------------------
// att[b,l,h*64+d] = Oacc / lacc  (fp32 -> bf16). 16 elems/thread.
// ---------------------------------------------------------------------------
__global__ __launch_bounds__(256) void normalize(const float* __restrict__ Oacc,
                                                 const float* __restrict__ lacc,
                                                 ushort_t* __restrict__ att)
{
    int t = blockIdx.x * 256 + threadIdx.x;   // 262144 threads
    int row = t >> 5;                          // 0..8191
    int col0 = (t & 31) * 16;
    int h = col0 >> 6;
    int b = row >> 12, l = row & (LSEQ - 1);
    float linv = 1.0f / lacc[((size_t)(b * NH + h)) * LSEQ + l];
    const float* o = &Oacc[(size_t)row * DH + col0];
    ushort_t tmp[16];
    #pragma unroll
    for (int j = 0; j < 16; j++) tmp[j] = f2bf(o[j] * linv);
    size_t g = (size_t)row * DH + col0;
    *(uint4*)&att[g]     = *(uint4*)&tmp[0];
    *(uint4*)&att[g + 8] = *(uint4*)&tmp[8];
}

// ---------------------------------------------------------------------------
extern "C" void kernel_launch(void* const* d_in, const int* in_sizes, int n_in,
                              void* d_out, int out_size, void* d_ws, size_t ws_size,
                              hipStream_t stream)
{
    const float* x     = (const float*)d_in[0];  // [2,4096,512]
    const float* w_in  = (const float*)d_in[1];  // [512,1536]
    const float* b_in  = (const float*)d_in[2];  // [1536]
    const float* w_out = (const float*)d_in[3];  // [512,512]
    const float* b_out = (const float*)d_in[4];  // [512]
    float* out = (float*)d_out;                  // [2,4096,512] fp32

    const int M = BSZ * LSEQ;                    // 8192
    char* ws = (char*)d_ws;
    ushort_t* xb    = (ushort_t*)ws;                       ws += (size_t)M * DH * 2;        // 8.4MB
    ushort_t* w_inT = (ushort_t*)ws;                       ws += (size_t)3 * DH * DH * 2;   // 1.6MB
    ushort_t* w_outT= (ushort_t*)ws;                       ws += (size_t)DH * DH * 2;       // 0.5MB
    ushort_t* qkvb  = (ushort_t*)ws;                       ws += (size_t)M * 3 * DH * 2;    // 25.2MB
    ushort_t* vtb   = (ushort_t*)ws;                       ws += (size_t)M * DH * 2;        // 8.4MB
    ushort_t* attb  = (ushort_t*)ws;                       ws += (size_t)M * DH * 2;        // 8.4MB
    float*    Oacc  = (float*)ws;                          ws += (size_t)M * DH * 4;        // 16.8MB
    float*    lacc  = (float*)ws;                          /* 256KB */

    prep<<<9280, 256, 0, stream>>>(x, xb, w_in, w_inT, w_out, w_outT, Oacc, lacc);

    // qkv GEMM: scales Q cols by C_EXP, writes V cols transposed into vtb
    gemm_bt<ushort_t, true, true><<<dim3(3 * DH / 128, M / 128), 256, 0, stream>>>(
        xb, w_inT, b_in, qkvb, vtb, M, 3 * DH, DH);

    flash_mfma<<<dim3(64, NH, BSZ), 128, 0, stream>>>(qkvb, vtb, Oacc, lacc);

    normalize<<<1024, 256, 0, stream>>>(Oacc, lacc, attb);

    gemm_bt<float, false, false><<<dim3(DH / 128, M / 128), 256, 0, stream>>>(
        attb, w_outT, b_out, out, nullptr, M, DH, DH);
}